// Round 1
// baseline (353.117 us; speedup 1.0000x reference)
//
#include <hip/hip_runtime.h>

// CombinedActorModel: B=1M elements, A=3 actors.
// One thread per batch element, fully-unrolled fp32 compute.
// Weights are wave-uniform (constant indices) -> compiler emits s_load into
// SGPRs; v_fma_f32 with SGPR src. No LDS. Only Wout rows 0..9 are needed.

#define NB 1048576

__global__ __launch_bounds__(256) void actor_fused(
    const float* __restrict__ spatial,
    const float* __restrict__ Wmx, const float* __restrict__ bmx,
    const float* __restrict__ Wnx, const float* __restrict__ bnx,
    const float* __restrict__ Wmy, const float* __restrict__ bmy,
    const float* __restrict__ Wny, const float* __restrict__ bny,
    const float* __restrict__ Wmz, const float* __restrict__ bmz,
    const float* __restrict__ Wnz, const float* __restrict__ bnz,
    const float* __restrict__ Wlin, const float* __restrict__ blin,
    const float* __restrict__ Wout, const float* __restrict__ bout,
    float* __restrict__ out, int nb)
{
    const int b = blockIdx.x * blockDim.x + threadIdx.x;
    if (b >= nb) return;

    // Load this element's 27 spatial features (plane x: 0..8, y: 9..17, z: 18..26)
    float s[27];
    const float* sp = spatial + (size_t)b * 27;
    #pragma unroll
    for (int i = 0; i < 27; ++i) s[i] = sp[i];

    float o9[3][10];   // head outputs 0..9 per actor (10..14 are never used)

    #pragma unroll
    for (int a = 0; a < 3; ++a) {
        float ps[25];

        // --- plane x: (s[0:6] @ Wmx[a].T + bmx) * (s[6:9] @ Wnx[a].T + bnx), 10 out
        #pragma unroll
        for (int o = 0; o < 10; ++o) {
            float m = bmx[a*10 + o];
            #pragma unroll
            for (int i = 0; i < 6; ++i) m = fmaf(s[i], Wmx[(a*10 + o)*6 + i], m);
            float n = bnx[a*10 + o];
            #pragma unroll
            for (int i = 0; i < 3; ++i) n = fmaf(s[6 + i], Wnx[(a*10 + o)*3 + i], n);
            ps[o] = m * n;
        }

        // --- plane y: s[9:15], s[15:18], 10 out
        #pragma unroll
        for (int o = 0; o < 10; ++o) {
            float m = bmy[a*10 + o];
            #pragma unroll
            for (int i = 0; i < 6; ++i) m = fmaf(s[9 + i], Wmy[(a*10 + o)*6 + i], m);
            float n = bny[a*10 + o];
            #pragma unroll
            for (int i = 0; i < 3; ++i) n = fmaf(s[15 + i], Wny[(a*10 + o)*3 + i], n);
            ps[10 + o] = m * n;
        }

        // --- plane z: s[18:24], s[24:27], 5 out
        #pragma unroll
        for (int o = 0; o < 5; ++o) {
            float m = bmz[a*5 + o];
            #pragma unroll
            for (int i = 0; i < 6; ++i) m = fmaf(s[18 + i], Wmz[(a*5 + o)*6 + i], m);
            float n = bnz[a*5 + o];
            #pragma unroll
            for (int i = 0; i < 3; ++i) n = fmaf(s[24 + i], Wnz[(a*5 + o)*3 + i], n);
            ps[20 + o] = m * n;
        }

        // --- 25x25 linear + softsign
        float h[25];
        #pragma unroll
        for (int o = 0; o < 25; ++o) {
            float acc = blin[a*25 + o];
            #pragma unroll
            for (int d = 0; d < 25; ++d)
                acc = fmaf(ps[d], Wlin[(a*25 + o)*25 + d], acc);
            // softsign: x / (1 + |x|), fast rcp (ulp-level error, threshold is 9.8e-3)
            h[o] = acc * __builtin_amdgcn_rcpf(1.0f + fabsf(acc));
        }

        // --- head: only outputs 0..9 are consumed downstream
        #pragma unroll
        for (int o = 0; o < 10; ++o) {
            float acc = bout[a*15 + o];
            #pragma unroll
            for (int d = 0; d < 25; ++d)
                acc = fmaf(h[d], Wout[(a*15 + o)*25 + d], acc);
            o9[a][o] = acc;
        }
    }

    // softmax over actors of channel 9
    float v0 = o9[0][9], v1 = o9[1][9], v2 = o9[2][9];
    float mx = fmaxf(v0, fmaxf(v1, v2));
    float e0 = __expf(v0 - mx);
    float e1 = __expf(v1 - mx);
    float e2 = __expf(v2 - mx);
    float inv = __builtin_amdgcn_rcpf(e0 + e1 + e2);

    float* op = out + (size_t)b * 9;
    #pragma unroll
    for (int o = 0; o < 9; ++o)
        op[o] = (o9[0][o]*e0 + o9[1][o]*e1 + o9[2][o]*e2) * inv;
}

extern "C" void kernel_launch(void* const* d_in, const int* in_sizes, int n_in,
                              void* d_out, int out_size, void* d_ws, size_t ws_size,
                              hipStream_t stream) {
    const float* spatial = (const float*)d_in[0];
    // d_in[1] = car_stats: unused by the model, never read.
    const float* Wmx  = (const float*)d_in[2];
    const float* bmx  = (const float*)d_in[3];
    const float* Wnx  = (const float*)d_in[4];
    const float* bnx  = (const float*)d_in[5];
    const float* Wmy  = (const float*)d_in[6];
    const float* bmy  = (const float*)d_in[7];
    const float* Wny  = (const float*)d_in[8];
    const float* bny  = (const float*)d_in[9];
    const float* Wmz  = (const float*)d_in[10];
    const float* bmz  = (const float*)d_in[11];
    const float* Wnz  = (const float*)d_in[12];
    const float* bnz  = (const float*)d_in[13];
    const float* Wlin = (const float*)d_in[14];
    const float* blin = (const float*)d_in[15];
    const float* Wout = (const float*)d_in[16];
    const float* bout = (const float*)d_in[17];
    float* out = (float*)d_out;

    const int nb = in_sizes[0] / 27;   // = 1048576
    dim3 grid((nb + 255) / 256);
    actor_fused<<<grid, dim3(256), 0, stream>>>(
        spatial,
        Wmx, bmx, Wnx, bnx,
        Wmy, bmy, Wny, bny,
        Wmz, bmz, Wnz, bnz,
        Wlin, blin, Wout, bout,
        out, nb);
}